// Round 13
// baseline (1329.141 us; speedup 1.0000x reference)
//
#include <hip/hip_runtime.h>
#include <math.h>

#define N_NODES 40000
#define MP      40192   // 157 * 256
#define NROWB   157
#define N_EDGES 640000
#define N_GRAPHS 64
#define F_IN 32
#define D_EMB 256
#define D_HID 512
#define D_FC 1024
#define N_CLS 10

typedef _Float16 f16x8 __attribute__((ext_vector_type(8)));
typedef float f32x4  __attribute__((ext_vector_type(4)));
typedef unsigned short u16;

__device__ __forceinline__ float h2f(u16 u) {
    union { u16 s; _Float16 h; } v; v.s = u; return (float)v.h;
}
__device__ __forceinline__ u16 f2h(float f) {
    union { u16 s; _Float16 h; } v; v.h = (_Float16)f; return v.s;
}
__device__ __forceinline__ void async16(void* lds, const void* g) {
    __builtin_amdgcn_global_load_lds((const __attribute__((address_space(1))) void*)g,
                                     (__attribute__((address_space(3))) void*)lds, 16, 0, 0);
}

// ---------------------------------------------------------------------------
__global__ void edge_mlp_deg(const float* __restrict__ edge_attr,
                             const float* __restrict__ ep_w1, const float* __restrict__ ep_b1,
                             const float* __restrict__ ep_w2, const float* __restrict__ ep_b2,
                             const int* __restrict__ dst,
                             float* __restrict__ ew, float* __restrict__ deg, int* __restrict__ cnt) {
    __shared__ float w1[64], b1[64], w2[64];
    int t = threadIdx.x;
    if (t < 64) { w1[t] = ep_w1[t]; b1[t] = ep_b1[t]; w2[t] = ep_w2[t]; }
    __syncthreads();
    int e = blockIdx.x * blockDim.x + t;
    if (e >= N_EDGES) return;
    float x = edge_attr[e];
    float s = ep_b2[0];
#pragma unroll
    for (int j = 0; j < 64; ++j) s += fmaxf(x * w1[j] + b1[j], 0.f) * w2[j];
    float sig = 1.f / (1.f + expf(-s));
    ew[e] = sig;
    int d = dst[e];
    atomicAdd(&deg[d], sig);
    atomicAdd(&cnt[d], 1);
}

// deg=1, cnt=0, cursor=0 in one pass
__global__ void init_kernel(float* __restrict__ deg, int* __restrict__ cnt, int* __restrict__ cursor) {
    int i = blockIdx.x * blockDim.x + threadIdx.x;
    if (i < N_NODES) { deg[i] = 1.0f; cnt[i] = 0; cursor[i] = 0; }
}

__global__ void dinv_kernel(const float* __restrict__ deg, float* __restrict__ dinv,
                            float* __restrict__ nloop) {
    int i = blockIdx.x * blockDim.x + threadIdx.x;
    if (i >= N_NODES) return;
    float d = deg[i];
    float r = (d > 0.f) ? rsqrtf(fmaxf(d, 1e-12f)) : 0.f;
    dinv[i] = r;
    nloop[i] = r * r;
}

__global__ void scan_kernel(const int* __restrict__ cnt, int* __restrict__ rowptr) {
    __shared__ int part[1024];
    int t = threadIdx.x;
    const int PER = (N_NODES + 1023) / 1024;
    int base = t * PER;
    int s = 0;
    for (int k = 0; k < PER; ++k) { int i = base + k; if (i < N_NODES) s += cnt[i]; }
    part[t] = s;
    __syncthreads();
    for (int off = 1; off < 1024; off <<= 1) {
        int v = (t >= off) ? part[t - off] : 0;
        __syncthreads();
        part[t] += v;
        __syncthreads();
    }
    int run = (t == 0) ? 0 : part[t - 1];
    for (int k = 0; k < PER; ++k) {
        int i = base + k;
        if (i < N_NODES) { rowptr[i] = run; run += cnt[i]; }
    }
    if (t == 1023) rowptr[N_NODES] = run;
}

__global__ void fill_csr_kernel(const int* __restrict__ src, const int* __restrict__ dst,
                                const float* __restrict__ ew, const float* __restrict__ dinv,
                                const int* __restrict__ rowptr, int* __restrict__ cursor,
                                int2* __restrict__ cv) {
    int e = blockIdx.x * blockDim.x + threadIdx.x;
    if (e >= N_EDGES) return;
    int d = dst[e];
    int s = src[e];
    float n = dinv[s] * ew[e] * dinv[d];
    int p = rowptr[d] + atomicAdd(&cursor[d], 1);
    cv[p] = make_int2(s, __float_as_int(n));
}

__global__ void wprep_kernel(const float* __restrict__ W, u16* __restrict__ Wt,
                             int K, int N) {
    __shared__ u16 th[32][33];
    int n0 = blockIdx.x * 32;
    int k0 = blockIdx.y * 32;
    int tx = threadIdx.x, ty = threadIdx.y;
#pragma unroll
    for (int r = 0; r < 4; ++r) {
        int k = ty + r * 8;
        th[k][tx] = f2h(W[(size_t)(k0 + k) * N + n0 + tx]);
    }
    __syncthreads();
#pragma unroll
    for (int r = 0; r < 4; ++r) {
        int n = ty + r * 8;
        Wt[(size_t)(n0 + n) * K + k0 + tx] = th[tx][n];
    }
}

__global__ void xprep_kernel(const float* __restrict__ x, u16* __restrict__ xb) {
    int idx = blockIdx.x * blockDim.x + threadIdx.x;
    if (idx >= MP * F_IN) return;
    int row = idx / F_IN;
    xb[idx] = (row < N_NODES) ? f2h(x[idx]) : (u16)0;
}

__global__ void gpad_zero(u16* __restrict__ G) {
    int i = blockIdx.x * blockDim.x + threadIdx.x;
    int total = (MP - N_NODES) * D_HID;
    if (i < total) G[(size_t)N_NODES * D_HID + i] = 0;
}

// ---------------------------------------------------------------------------
// MFMA GEMM (fp16), BM=256 x BN=256, BK=32, 1024 threads (16 waves, 4x4 of
// 64x64). LDS 2 x (16KB A + 16KB W) = 64 KB dbuf. 2 async16/wave/iter.
// Tile-traffic: M*N*K*2*(1/256+1/256) — 33% less than BM256xBN128.
// ---------------------------------------------------------------------------
__launch_bounds__(1024, 4)
__global__ void mfma_gemm(const u16* __restrict__ A,
                          const u16* __restrict__ W,
                          const float* __restrict__ bias,
                          const u16* __restrict__ skip,
                          u16* __restrict__ C, int K, int N) {
    __shared__ __align__(16) u16 smem[2 * 16384];   // 64 KB

    int nColB = N >> 8;            // 256->1, 512->2
    int b = blockIdx.x;
    int rowI = (b >> 3) / nColB * 8 + (b & 7);
    int colI = (b >> 3) % nColB;
    if (rowI >= NROWB) return;
    int rowBase = rowI * 256;
    int colBase = colI * 256;

    int t = threadIdx.x;
    int lane = t & 63;
    int wave = t >> 6;             // 0..15
    int wr = wave >> 2;            // 0..3
    int wc = wave & 3;             // 0..3

    // staging inverse-swizzle mapping: lane L writes LDS at group_base + L*16B
    int tt  = (lane & 7) ^ ((lane >> 3) & 7);
    int rrl = ((lane >> 3) << 1) | (tt >> 2);
    int sel = (tt & 3) * 8;
    int r0 = wave * 16;            // each wave stages 16 rows of A and of W

    int quad = lane >> 4;
    int mrow = lane & 15;

    const u16* gA = A + (size_t)(rowBase + r0 + rrl) * K + sel;
    const u16* gW = W + (size_t)(colBase + r0 + rrl) * K + sel;

    f32x4 acc[4][4] = {};
    int nIter = K >> 5;
    {
        u16* As = smem; u16* Ws = smem + 8192;
        async16(&As[r0 * 32], gA);
        async16(&Ws[r0 * 32], gW);
    }
    for (int it = 0; it < nIter; ++it) {
        int cur = it & 1;
        __syncthreads();           // buffer `cur` ready (DMA had a full compute phase)
        if (it + 1 < nIter) {
            int k0 = (it + 1) << 5;
            u16* As = smem + (cur ^ 1) * 16384; u16* Ws = As + 8192;
            async16(&As[r0 * 32], gA + k0);
            async16(&Ws[r0 * 32], gW + k0);
        }
        const u16* As = smem + cur * 16384;
        const u16* Ws = As + 8192;
        f16x8 af[4], wf[4];
#pragma unroll
        for (int i = 0; i < 4; ++i) {
            int Ra = wr * 64 + i * 16 + mrow;
            int sa = ((Ra & 1) * 4 + quad) ^ ((Ra >> 1) & 7);
            af[i] = *(const f16x8*)&As[(Ra >> 1) * 64 + sa * 8];
            int Rb = wc * 64 + i * 16 + mrow;
            int sb = ((Rb & 1) * 4 + quad) ^ ((Rb >> 1) & 7);
            wf[i] = *(const f16x8*)&Ws[(Rb >> 1) * 64 + sb * 8];
        }
#pragma unroll
        for (int i = 0; i < 4; ++i)
#pragma unroll
            for (int j = 0; j < 4; ++j)
                acc[i][j] = __builtin_amdgcn_mfma_f32_16x16x32_f16(af[i], wf[j], acc[i][j], 0, 0, 0);
    }
    __syncthreads();

    // epilogue: 4 phases of 64 rows; bias/relu/skip -> LDS (stride 264) -> coalesced
    const int ES = 264;            // 256 + 8 pad; row stride 528B, 16B-aligned
    u16* eb = smem;
#pragma unroll
    for (int ph = 0; ph < 4; ++ph) {
        if (wr == ph) {
#pragma unroll
            for (int j = 0; j < 4; ++j) {
                int lcol = wc * 64 + j * 16 + mrow;
                int col = colBase + lcol;
                float bv = bias[col];
#pragma unroll
                for (int i = 0; i < 4; ++i) {
#pragma unroll
                    for (int r = 0; r < 4; ++r) {
                        int lr = i * 16 + quad * 4 + r;
                        size_t row = (size_t)rowBase + ph * 64 + lr;
                        float v = fmaxf(acc[i][j][r] + bv, 0.f);
                        if (skip) v += h2f(skip[row * N + col]);
                        eb[lr * ES + lcol] = f2h(v);
                    }
                }
            }
        }
        __syncthreads();
#pragma unroll
        for (int k = 0; k < 2; ++k) {
            int c = t + k * 1024;      // 0..2047 = 64 rows x 32 chunks
            int row = c >> 5;
            int ch = c & 31;
            f16x8 v = *(const f16x8*)&eb[row * ES + ch * 8];
            *(f16x8*)&C[(size_t)(rowBase + ph * 64 + row) * N + colBase + ch * 8] = v;
        }
        __syncthreads();
    }
}

// ---------------------------------------------------------------------------
// row gather (fp16 in/out, fp32 accum): one wave per node, 8-deep edge ILP.
// ---------------------------------------------------------------------------
template <int D>
__global__ void gather_f16(const u16* __restrict__ h, const int* __restrict__ rowptr,
                           const int2* __restrict__ cv, const float* __restrict__ nloop,
                           u16* __restrict__ out) {
    constexpr int FPL = D / 64;
    constexpr int UPL = FPL / 2;
    int node = blockIdx.x * 4 + (threadIdx.x >> 6);
    int lane = threadIdx.x & 63;
    if (node >= N_NODES) return;
    const unsigned* hrow = (const unsigned*)(h + (size_t)node * D + lane * FPL);
    float acc[FPL];
    float sl = nloop[node];
    union U { unsigned w; _Float16 h[2]; };
    U tv[8][UPL];
#pragma unroll
    for (int u = 0; u < UPL; ++u) tv[0][u].w = hrow[u];
#pragma unroll
    for (int u = 0; u < UPL; ++u) {
        acc[2 * u]     = (float)tv[0][u].h[0] * sl;
        acc[2 * u + 1] = (float)tv[0][u].h[1] * sl;
    }
    int beg = rowptr[node], end = rowptr[node + 1];
    int j = beg;
    for (; j + 8 <= end; j += 8) {
        int2 c[8];
        const unsigned* xp[8];
#pragma unroll
        for (int m = 0; m < 8; ++m) c[m] = cv[j + m];
#pragma unroll
        for (int m = 0; m < 8; ++m) xp[m] = (const unsigned*)(h + (size_t)c[m].x * D + lane * FPL);
#pragma unroll
        for (int m = 0; m < 8; ++m)
#pragma unroll
            for (int u = 0; u < UPL; ++u) tv[m][u].w = xp[m][u];
#pragma unroll
        for (int m = 0; m < 8; ++m) {
            float v = __int_as_float(c[m].y);
#pragma unroll
            for (int u = 0; u < UPL; ++u) {
                acc[2 * u]     += (float)tv[m][u].h[0] * v;
                acc[2 * u + 1] += (float)tv[m][u].h[1] * v;
            }
        }
    }
    for (; j + 2 <= end; j += 2) {
        int2 c0 = cv[j], c1 = cv[j + 1];
        const unsigned* x0 = (const unsigned*)(h + (size_t)c0.x * D + lane * FPL);
        const unsigned* x1 = (const unsigned*)(h + (size_t)c1.x * D + lane * FPL);
#pragma unroll
        for (int u = 0; u < UPL; ++u) tv[0][u].w = x0[u];
#pragma unroll
        for (int u = 0; u < UPL; ++u) tv[1][u].w = x1[u];
        float v0 = __int_as_float(c0.y), v1 = __int_as_float(c1.y);
#pragma unroll
        for (int u = 0; u < UPL; ++u) {
            acc[2 * u]     += (float)tv[0][u].h[0] * v0 + (float)tv[1][u].h[0] * v1;
            acc[2 * u + 1] += (float)tv[0][u].h[1] * v0 + (float)tv[1][u].h[1] * v1;
        }
    }
    if (j < end) {
        int2 c0 = cv[j];
        const unsigned* x0 = (const unsigned*)(h + (size_t)c0.x * D + lane * FPL);
#pragma unroll
        for (int u = 0; u < UPL; ++u) tv[0][u].w = x0[u];
        float v0 = __int_as_float(c0.y);
#pragma unroll
        for (int u = 0; u < UPL; ++u) {
            acc[2 * u]     += (float)tv[0][u].h[0] * v0;
            acc[2 * u + 1] += (float)tv[0][u].h[1] * v0;
        }
    }
    unsigned* orow = (unsigned*)(out + (size_t)node * D + lane * FPL);
#pragma unroll
    for (int u = 0; u < UPL; ++u) {
        unsigned lo = f2h(acc[2 * u]);
        unsigned hi = f2h(acc[2 * u + 1]);
        orow[u] = lo | (hi << 16);
    }
}

#define NP 50
__global__ void pool_sum_f16(const u16* __restrict__ x, const int* __restrict__ batch,
                             float* __restrict__ sums) {
    int t = blockIdx.x * blockDim.x + threadIdx.x;
    int total = (N_NODES / NP) * D_HID;
    if (t >= total) return;
    int d = t % D_HID;
    int group = t / D_HID;
    int n0 = group * NP;
    float acc = 0.f;
    int g = batch[n0];
    for (int k = 0; k < NP; ++k) {
        int n = n0 + k;
        int bg = batch[n];
        if (bg != g) { atomicAdd(&sums[(size_t)g * D_HID + d], acc); acc = 0.f; g = bg; }
        acc += h2f(x[(size_t)n * D_HID + d]);
    }
    atomicAdd(&sums[(size_t)g * D_HID + d], acc);
}

__global__ void graph_cnt_kernel(const int* __restrict__ batch, float* __restrict__ cnts) {
    int g = threadIdx.x;
    if (g >= N_GRAPHS) return;
    int lo = 0, hi = N_NODES;
    while (lo < hi) { int m = (lo + hi) >> 1; if (batch[m] < g) lo = m + 1; else hi = m; }
    int lb = lo;
    lo = lb; hi = N_NODES;
    while (lo < hi) { int m = (lo + hi) >> 1; if (batch[m] < g + 1) lo = m + 1; else hi = m; }
    cnts[g] = (float)(lo - lb);
}

__global__ void zero2_kernel(float* __restrict__ p1, int n1, float* __restrict__ p2, int n2) {
    int i = blockIdx.x * blockDim.x + threadIdx.x;
    if (i < n1) p1[i] = 0.f;
    else if (i < n1 + n2) p2[i - n1] = 0.f;
}

__launch_bounds__(256)
__global__ void fc1_part(const float* __restrict__ sums, const float* __restrict__ cnts,
                         const float* __restrict__ fc1_w, float* __restrict__ F) {
    __shared__ float sv[64];
    int b = blockIdx.x;
    int g = b >> 3;
    int kc = b & 7;
    int t = threadIdx.x;
    if (t < 64) sv[t] = sums[(size_t)g * D_HID + kc * 64 + t] / fmaxf(cnts[g], 1.f);
    __syncthreads();
#pragma unroll
    for (int m = 0; m < D_FC / 256; ++m) {
        int j = t + m * 256;
        const float* wp = fc1_w + (size_t)(kc * 64) * D_FC + j;
        float acc = 0.f;
#pragma unroll
        for (int k = 0; k < 64; ++k) acc += sv[k] * wp[(size_t)k * D_FC];
        atomicAdd(&F[(size_t)g * D_FC + j], acc);
    }
}

__launch_bounds__(256)
__global__ void head_final(const float* __restrict__ F, const float* __restrict__ fc1_b,
                           const float* __restrict__ head_w, const float* __restrict__ head_b,
                           float* __restrict__ out) {
    __shared__ float hacc[N_CLS];
    int g = blockIdx.x;
    int t = threadIdx.x;
    if (t < N_CLS) hacc[t] = 0.f;
    __syncthreads();
    float p[N_CLS] = {};
    for (int j = t; j < D_FC; j += 256) {
        float f = fmaxf(F[(size_t)g * D_FC + j] + fc1_b[j], 0.f);
#pragma unroll
        for (int c = 0; c < N_CLS; ++c) p[c] += f * head_w[j * N_CLS + c];
    }
#pragma unroll
    for (int c = 0; c < N_CLS; ++c) {
        float v = p[c];
        for (int off = 32; off; off >>= 1) v += __shfl_down(v, off, 64);
        if ((t & 63) == 0) atomicAdd(&hacc[c], v);
    }
    __syncthreads();
    if (t < N_CLS) out[g * N_CLS + t] = hacc[t] + head_b[t];
}

extern "C" void kernel_launch(void* const* d_in, const int* in_sizes, int n_in,
                              void* d_out, int out_size, void* d_ws, size_t ws_size,
                              hipStream_t stream) {
    const float* x          = (const float*)d_in[0];
    const int*   edge_index = (const int*)d_in[1];
    const float* edge_attr  = (const float*)d_in[2];
    const int*   batch      = (const int*)d_in[3];
    const float* emb_w1 = (const float*)d_in[4];
    const float* emb_b1 = (const float*)d_in[5];
    const float* emb_w2 = (const float*)d_in[6];
    const float* emb_b2 = (const float*)d_in[7];
    const float* ep_w1  = (const float*)d_in[8];
    const float* ep_b1  = (const float*)d_in[9];
    const float* ep_w2  = (const float*)d_in[10];
    const float* ep_b2  = (const float*)d_in[11];
    const float* w_c[6] = { (const float*)d_in[12], (const float*)d_in[14], (const float*)d_in[16],
                            (const float*)d_in[18], (const float*)d_in[20], (const float*)d_in[22] };
    const float* b_c[6] = { (const float*)d_in[13], (const float*)d_in[15], (const float*)d_in[17],
                            (const float*)d_in[19], (const float*)d_in[21], (const float*)d_in[23] };
    const float* fc1_w  = (const float*)d_in[24];
    const float* fc1_b  = (const float*)d_in[25];
    const float* head_w = (const float*)d_in[26];
    const float* head_b = (const float*)d_in[27];
    float* out = (float*)d_out;

    const int* src = edge_index;
    const int* dst = edge_index + N_EDGES;

    char* p = (char*)d_ws;
    auto alloc = [&](size_t bytes) { char* r = p; p += (bytes + 255) & ~(size_t)255; return r; };
    float* ew    = (float*)alloc(N_EDGES * 4);
    float* deg   = (float*)alloc(N_NODES * 4);
    float* dinv  = (float*)alloc(N_NODES * 4);
    float* nloop = (float*)alloc(N_NODES * 4);
    int* cnt     = (int*)alloc(N_NODES * 4);
    int* cursor  = (int*)alloc(N_NODES * 4);
    int* rowptr  = (int*)alloc((N_NODES + 1) * 4);
    int2* cv     = (int2*)alloc((size_t)N_EDGES * 8);
    u16* xb = (u16*)alloc((size_t)MP * F_IN * 2);
    u16* H1 = (u16*)alloc((size_t)MP * D_EMB * 2);
    u16* H2 = (u16*)alloc((size_t)MP * D_EMB * 2);
    u16* G  = (u16*)alloc((size_t)MP * D_HID * 2);
    u16* S1 = (u16*)alloc((size_t)MP * D_HID * 2);
    u16* S2 = (u16*)alloc((size_t)MP * D_HID * 2);
    u16* Cb = (u16*)alloc((size_t)MP * D_HID * 2);
    u16* we1 = (u16*)alloc((size_t)F_IN * D_EMB * 2);
    u16* we2 = (u16*)alloc((size_t)D_EMB * D_EMB * 2);
    u16* wc[6];
    wc[0] = (u16*)alloc((size_t)D_EMB * D_HID * 2);
    for (int i = 1; i < 6; ++i) wc[i] = (u16*)alloc((size_t)D_HID * D_HID * 2);
    float* sums = (float*)alloc(N_GRAPHS * D_HID * 4);
    float* cnts = (float*)alloc(N_GRAPHS * 4);
    float* F    = (float*)alloc(N_GRAPHS * D_FC * 4);

    const int TB = 256;
    const int EB = (N_EDGES + TB - 1) / TB;
    const int NB = (N_NODES + TB - 1) / TB;

    init_kernel<<<NB, TB, 0, stream>>>(deg, cnt, cursor);
    edge_mlp_deg<<<EB, TB, 0, stream>>>(edge_attr, ep_w1, ep_b1, ep_w2, ep_b2, dst, ew, deg, cnt);
    dinv_kernel<<<NB, TB, 0, stream>>>(deg, dinv, nloop);
    scan_kernel<<<1, 1024, 0, stream>>>(cnt, rowptr);
    fill_csr_kernel<<<EB, TB, 0, stream>>>(src, dst, ew, dinv, rowptr, cursor, cv);

    xprep_kernel<<<(MP * F_IN + TB - 1) / TB, TB, 0, stream>>>(x, xb);
    gpad_zero<<<((MP - N_NODES) * D_HID + TB - 1) / TB, TB, 0, stream>>>(G);
    wprep_kernel<<<dim3(D_EMB / 32, F_IN / 32), dim3(32, 8), 0, stream>>>(emb_w1, we1, F_IN, D_EMB);
    wprep_kernel<<<dim3(D_EMB / 32, D_EMB / 32), dim3(32, 8), 0, stream>>>(emb_w2, we2, D_EMB, D_EMB);
    wprep_kernel<<<dim3(D_HID / 32, D_EMB / 32), dim3(32, 8), 0, stream>>>(w_c[0], wc[0], D_EMB, D_HID);
    for (int i = 1; i < 6; ++i)
        wprep_kernel<<<dim3(D_HID / 32, D_HID / 32), dim3(32, 8), 0, stream>>>(w_c[i], wc[i], D_HID, D_HID);

    const int SLOTS = ((NROWB + 7) / 8) * 8;        // 160
    const int GRID2 = SLOTS * (D_EMB / 256);        // 160 (nColB=1)
    const int GRID4 = SLOTS * (D_HID / 256);        // 320 (nColB=2)
    mfma_gemm<<<GRID2, 1024, 0, stream>>>(xb, we1, emb_b1, nullptr, H1, F_IN, D_EMB);
    mfma_gemm<<<GRID2, 1024, 0, stream>>>(H1, we2, emb_b2, nullptr, H2, D_EMB, D_EMB);

    const int GG = (N_NODES + 3) / 4;
    gather_f16<D_EMB><<<GG, 256, 0, stream>>>(H2, rowptr, cv, nloop, G);
    mfma_gemm<<<GRID4, 1024, 0, stream>>>(G, wc[0], b_c[0], nullptr, S1, D_EMB, D_HID);
    gather_f16<D_HID><<<GG, 256, 0, stream>>>(S1, rowptr, cv, nloop, G);
    mfma_gemm<<<GRID4, 1024, 0, stream>>>(G, wc[1], b_c[1], nullptr, Cb, D_HID, D_HID);
    gather_f16<D_HID><<<GG, 256, 0, stream>>>(Cb, rowptr, cv, nloop, G);
    mfma_gemm<<<GRID4, 1024, 0, stream>>>(G, wc[2], b_c[2], S1, S2, D_HID, D_HID);
    gather_f16<D_HID><<<GG, 256, 0, stream>>>(S2, rowptr, cv, nloop, G);
    mfma_gemm<<<GRID4, 1024, 0, stream>>>(G, wc[3], b_c[3], nullptr, Cb, D_HID, D_HID);
    gather_f16<D_HID><<<GG, 256, 0, stream>>>(Cb, rowptr, cv, nloop, G);
    mfma_gemm<<<GRID4, 1024, 0, stream>>>(G, wc[4], b_c[4], nullptr, Cb, D_HID, D_HID);
    gather_f16<D_HID><<<GG, 256, 0, stream>>>(Cb, rowptr, cv, nloop, G);
    mfma_gemm<<<GRID4, 1024, 0, stream>>>(G, wc[5], b_c[5], S2, Cb, D_HID, D_HID);

    zero2_kernel<<<(N_GRAPHS * (D_HID + D_FC) + TB - 1) / TB, TB, 0, stream>>>(
        sums, N_GRAPHS * D_HID, F, N_GRAPHS * D_FC);
    pool_sum_f16<<<((N_NODES / NP) * D_HID + TB - 1) / TB, TB, 0, stream>>>(Cb, batch, sums);
    graph_cnt_kernel<<<1, 64, 0, stream>>>(batch, cnts);
    fc1_part<<<N_GRAPHS * 8, 256, 0, stream>>>(sums, cnts, fc1_w, F);
    head_final<<<N_GRAPHS, 256, 0, stream>>>(F, fc1_b, head_w, head_b, out);
}

// Round 14
// 1203.689 us; speedup vs baseline: 1.1042x; 1.1042x over previous
//
#include <hip/hip_runtime.h>
#include <math.h>

#define N_NODES 40000
#define MP      40192   // 157 * 256
#define NROWB   157
#define N_EDGES 640000
#define N_GRAPHS 64
#define F_IN 32
#define D_EMB 256
#define D_HID 512
#define D_FC 1024
#define N_CLS 10

typedef _Float16 f16x8 __attribute__((ext_vector_type(8)));
typedef float f32x4  __attribute__((ext_vector_type(4)));
typedef unsigned short u16;

template <int N> struct VecU;
template <> struct VecU<2> { typedef unsigned T __attribute__((ext_vector_type(2))); };
template <> struct VecU<4> { typedef unsigned T __attribute__((ext_vector_type(4))); };

__device__ __forceinline__ float h2f(u16 u) {
    union { u16 s; _Float16 h; } v; v.s = u; return (float)v.h;
}
__device__ __forceinline__ u16 f2h(float f) {
    union { u16 s; _Float16 h; } v; v.h = (_Float16)f; return v.s;
}
__device__ __forceinline__ void async16(void* lds, const void* g) {
    __builtin_amdgcn_global_load_lds((const __attribute__((address_space(1))) void*)g,
                                     (__attribute__((address_space(3))) void*)lds, 16, 0, 0);
}

// ---------------------------------------------------------------------------
__global__ void edge_mlp_deg(const float* __restrict__ edge_attr,
                             const float* __restrict__ ep_w1, const float* __restrict__ ep_b1,
                             const float* __restrict__ ep_w2, const float* __restrict__ ep_b2,
                             const int* __restrict__ dst,
                             float* __restrict__ ew, float* __restrict__ deg, int* __restrict__ cnt) {
    __shared__ float w1[64], b1[64], w2[64];
    int t = threadIdx.x;
    if (t < 64) { w1[t] = ep_w1[t]; b1[t] = ep_b1[t]; w2[t] = ep_w2[t]; }
    __syncthreads();
    int e = blockIdx.x * blockDim.x + t;
    if (e >= N_EDGES) return;
    float x = edge_attr[e];
    float s = ep_b2[0];
#pragma unroll
    for (int j = 0; j < 64; ++j) s += fmaxf(x * w1[j] + b1[j], 0.f) * w2[j];
    float sig = 1.f / (1.f + expf(-s));
    ew[e] = sig;
    int d = dst[e];
    atomicAdd(&deg[d], sig);
    atomicAdd(&cnt[d], 1);
}

__global__ void init_kernel(float* __restrict__ deg, int* __restrict__ cnt, int* __restrict__ cursor) {
    int i = blockIdx.x * blockDim.x + threadIdx.x;
    if (i < N_NODES) { deg[i] = 1.0f; cnt[i] = 0; cursor[i] = 0; }
}

__global__ void dinv_kernel(const float* __restrict__ deg, float* __restrict__ dinv,
                            float* __restrict__ nloop) {
    int i = blockIdx.x * blockDim.x + threadIdx.x;
    if (i >= N_NODES) return;
    float d = deg[i];
    float r = (d > 0.f) ? rsqrtf(fmaxf(d, 1e-12f)) : 0.f;
    dinv[i] = r;
    nloop[i] = r * r;
}

__global__ void scan_kernel(const int* __restrict__ cnt, int* __restrict__ rowptr) {
    __shared__ int part[1024];
    int t = threadIdx.x;
    const int PER = (N_NODES + 1023) / 1024;
    int base = t * PER;
    int s = 0;
    for (int k = 0; k < PER; ++k) { int i = base + k; if (i < N_NODES) s += cnt[i]; }
    part[t] = s;
    __syncthreads();
    for (int off = 1; off < 1024; off <<= 1) {
        int v = (t >= off) ? part[t - off] : 0;
        __syncthreads();
        part[t] += v;
        __syncthreads();
    }
    int run = (t == 0) ? 0 : part[t - 1];
    for (int k = 0; k < PER; ++k) {
        int i = base + k;
        if (i < N_NODES) { rowptr[i] = run; run += cnt[i]; }
    }
    if (t == 1023) rowptr[N_NODES] = run;
}

__global__ void fill_csr_kernel(const int* __restrict__ src, const int* __restrict__ dst,
                                const float* __restrict__ ew, const float* __restrict__ dinv,
                                const int* __restrict__ rowptr, int* __restrict__ cursor,
                                int2* __restrict__ cv) {
    int e = blockIdx.x * blockDim.x + threadIdx.x;
    if (e >= N_EDGES) return;
    int d = dst[e];
    int s = src[e];
    float n = dinv[s] * ew[e] * dinv[d];
    int p = rowptr[d] + atomicAdd(&cursor[d], 1);
    cv[p] = make_int2(s, __float_as_int(n));
}

__global__ void wprep_kernel(const float* __restrict__ W, u16* __restrict__ Wt,
                             int K, int N) {
    __shared__ u16 th[32][33];
    int n0 = blockIdx.x * 32;
    int k0 = blockIdx.y * 32;
    int tx = threadIdx.x, ty = threadIdx.y;
#pragma unroll
    for (int r = 0; r < 4; ++r) {
        int k = ty + r * 8;
        th[k][tx] = f2h(W[(size_t)(k0 + k) * N + n0 + tx]);
    }
    __syncthreads();
#pragma unroll
    for (int r = 0; r < 4; ++r) {
        int n = ty + r * 8;
        Wt[(size_t)(n0 + n) * K + k0 + tx] = th[tx][n];
    }
}

__global__ void xprep_kernel(const float* __restrict__ x, u16* __restrict__ xb) {
    int idx = blockIdx.x * blockDim.x + threadIdx.x;
    if (idx >= MP * F_IN) return;
    int row = idx / F_IN;
    xb[idx] = (row < N_NODES) ? f2h(x[idx]) : (u16)0;
}

__global__ void gpad_zero(u16* __restrict__ G) {
    int i = blockIdx.x * blockDim.x + threadIdx.x;
    int total = (MP - N_NODES) * D_HID;
    if (i < total) G[(size_t)N_NODES * D_HID + i] = 0;
}

// ---------------------------------------------------------------------------
// MFMA GEMM (fp16), BM=256 x BN=128, BK=32, 512 threads (8 waves) — R12 proven.
// XOR-swizzled LDS, double-buffered DMA, 1 barrier/iter, XCD-affinity swizzle.
// ---------------------------------------------------------------------------
__launch_bounds__(512)
__global__ void mfma_gemm(const u16* __restrict__ A,
                          const u16* __restrict__ W,
                          const float* __restrict__ bias,
                          const u16* __restrict__ skip,
                          u16* __restrict__ C, int K, int N) {
    __shared__ __align__(16) u16 smem[2 * 12288];   // 48 KB

    int nColB = N >> 7;
    int b = blockIdx.x;
    int rowI = (b >> 3) / nColB * 8 + (b & 7);
    int colI = (b >> 3) % nColB;
    if (rowI >= NROWB) return;
    int rowBase = rowI * 256;
    int colBase = colI * 128;

    int t = threadIdx.x;
    int lane = t & 63;
    int wave = t >> 6;
    int wr = wave >> 1;
    int wc = wave & 1;

    int tt  = (lane & 7) ^ ((lane >> 3) & 7);
    int rrl = ((lane >> 3) << 1) | (tt >> 2);
    int sel = (tt & 3) * 8;
    int r0A = wave * 32;
    int r0W = wave * 16;

    int quad = lane >> 4;
    int mrow = lane & 15;

    const u16* gA = A + (size_t)(rowBase + r0A + rrl) * K + sel;
    const u16* gW = W + (size_t)(colBase + r0W + rrl) * K + sel;

    f32x4 acc[4][4] = {};

    int nIter = K >> 5;
    {
        u16* As = smem; u16* Ws = smem + 8192;
        async16(&As[r0A * 32], gA);
        async16(&As[(r0A + 16) * 32], gA + (size_t)16 * K);
        async16(&Ws[r0W * 32], gW);
    }

    for (int it = 0; it < nIter; ++it) {
        int cur = it & 1;
        __syncthreads();
        if (it + 1 < nIter) {
            int k0 = (it + 1) << 5;
            u16* As = smem + (cur ^ 1) * 12288; u16* Ws = As + 8192;
            async16(&As[r0A * 32], gA + k0);
            async16(&As[(r0A + 16) * 32], gA + k0 + (size_t)16 * K);
            async16(&Ws[r0W * 32], gW + k0);
        }
        const u16* As = smem + cur * 12288;
        const u16* Ws = As + 8192;
        f16x8 af[4], wf[4];
#pragma unroll
        for (int i = 0; i < 4; ++i) {
            int Ra = wr * 64 + i * 16 + mrow;
            int sa = ((Ra & 1) * 4 + quad) ^ ((Ra >> 1) & 7);
            af[i] = *(const f16x8*)&As[(Ra >> 1) * 64 + sa * 8];
            int Rb = wc * 64 + i * 16 + mrow;
            int sb = ((Rb & 1) * 4 + quad) ^ ((Rb >> 1) & 7);
            wf[i] = *(const f16x8*)&Ws[(Rb >> 1) * 64 + sb * 8];
        }
#pragma unroll
        for (int i = 0; i < 4; ++i)
#pragma unroll
            for (int j = 0; j < 4; ++j)
                acc[i][j] = __builtin_amdgcn_mfma_f32_16x16x32_f16(af[i], wf[j], acc[i][j], 0, 0, 0);
    }
    __syncthreads();

    const int ES = 132;
    u16* eb = smem;
#pragma unroll
    for (int ph = 0; ph < 2; ++ph) {
        if ((wr >> 1) == ph) {
#pragma unroll
            for (int j = 0; j < 4; ++j) {
                int col = colBase + wc * 64 + j * 16 + mrow;
                float bv = bias[col];
#pragma unroll
                for (int i = 0; i < 4; ++i) {
#pragma unroll
                    for (int r = 0; r < 4; ++r) {
                        int lr = (wr & 1) * 64 + i * 16 + quad * 4 + r;
                        size_t row = (size_t)rowBase + ph * 128 + lr;
                        float v = fmaxf(acc[i][j][r] + bv, 0.f);
                        if (skip) v += h2f(skip[row * N + col]);
                        eb[lr * ES + wc * 64 + j * 16 + mrow] = f2h(v);
                    }
                }
            }
        }
        __syncthreads();
#pragma unroll
        for (int k = 0; k < 4; ++k) {
            int c = t + k * 512;
            int row = c >> 4;
            int ch = c & 15;
            f16x8 v = *(const f16x8*)&eb[row * ES + ch * 8];
            *(f16x8*)&C[(size_t)(rowBase + ph * 128 + row) * N + colBase + ch * 8] = v;
        }
        __syncthreads();
    }
}

// ---------------------------------------------------------------------------
// row gather (fp16 in/out, fp32 accum): one wave per node, 8-deep edge ILP,
// explicit 16B (D=512) / 8B (D=256) vector loads per edge per lane.
// ---------------------------------------------------------------------------
template <int D>
__global__ void gather_f16(const u16* __restrict__ h, const int* __restrict__ rowptr,
                           const int2* __restrict__ cv, const float* __restrict__ nloop,
                           u16* __restrict__ out) {
    constexpr int FPL = D / 64;
    constexpr int UPL = FPL / 2;
    using VU = typename VecU<UPL>::T;
    int node = blockIdx.x * 4 + (threadIdx.x >> 6);
    int lane = threadIdx.x & 63;
    if (node >= N_NODES) return;
    union UU { unsigned u; _Float16 h[2]; };
    float acc[FPL];
    float sl = nloop[node];
    {
        VU own = *(const VU*)(h + (size_t)node * D + lane * FPL);
#pragma unroll
        for (int u = 0; u < UPL; ++u) {
            UU w; w.u = own[u];
            acc[2 * u]     = (float)w.h[0] * sl;
            acc[2 * u + 1] = (float)w.h[1] * sl;
        }
    }
    int beg = rowptr[node], end = rowptr[node + 1];
    int j = beg;
    for (; j + 8 <= end; j += 8) {
        int2 c[8];
#pragma unroll
        for (int m = 0; m < 8; ++m) c[m] = cv[j + m];
        VU tv[8];
#pragma unroll
        for (int m = 0; m < 8; ++m)
            tv[m] = *(const VU*)(h + (size_t)c[m].x * D + lane * FPL);
#pragma unroll
        for (int m = 0; m < 8; ++m) {
            float v = __int_as_float(c[m].y);
#pragma unroll
            for (int u = 0; u < UPL; ++u) {
                UU w; w.u = tv[m][u];
                acc[2 * u]     += (float)w.h[0] * v;
                acc[2 * u + 1] += (float)w.h[1] * v;
            }
        }
    }
    for (; j + 2 <= end; j += 2) {
        int2 c0 = cv[j], c1 = cv[j + 1];
        VU t0 = *(const VU*)(h + (size_t)c0.x * D + lane * FPL);
        VU t1 = *(const VU*)(h + (size_t)c1.x * D + lane * FPL);
        float v0 = __int_as_float(c0.y), v1 = __int_as_float(c1.y);
#pragma unroll
        for (int u = 0; u < UPL; ++u) {
            UU w0; w0.u = t0[u];
            UU w1; w1.u = t1[u];
            acc[2 * u]     += (float)w0.h[0] * v0 + (float)w1.h[0] * v1;
            acc[2 * u + 1] += (float)w0.h[1] * v0 + (float)w1.h[1] * v1;
        }
    }
    if (j < end) {
        int2 c0 = cv[j];
        VU t0 = *(const VU*)(h + (size_t)c0.x * D + lane * FPL);
        float v0 = __int_as_float(c0.y);
#pragma unroll
        for (int u = 0; u < UPL; ++u) {
            UU w0; w0.u = t0[u];
            acc[2 * u]     += (float)w0.h[0] * v0;
            acc[2 * u + 1] += (float)w0.h[1] * v0;
        }
    }
    VU o;
#pragma unroll
    for (int u = 0; u < UPL; ++u) {
        unsigned lo = f2h(acc[2 * u]);
        unsigned hi = f2h(acc[2 * u + 1]);
        o[u] = lo | (hi << 16);
    }
    *(VU*)(out + (size_t)node * D + lane * FPL) = o;
}

#define NP 50
__global__ void pool_sum_f16(const u16* __restrict__ x, const int* __restrict__ batch,
                             float* __restrict__ sums) {
    int t = blockIdx.x * blockDim.x + threadIdx.x;
    int total = (N_NODES / NP) * D_HID;
    if (t >= total) return;
    int d = t % D_HID;
    int group = t / D_HID;
    int n0 = group * NP;
    float acc = 0.f;
    int g = batch[n0];
    for (int k = 0; k < NP; ++k) {
        int n = n0 + k;
        int bg = batch[n];
        if (bg != g) { atomicAdd(&sums[(size_t)g * D_HID + d], acc); acc = 0.f; g = bg; }
        acc += h2f(x[(size_t)n * D_HID + d]);
    }
    atomicAdd(&sums[(size_t)g * D_HID + d], acc);
}

__global__ void graph_cnt_kernel(const int* __restrict__ batch, float* __restrict__ cnts) {
    int g = threadIdx.x;
    if (g >= N_GRAPHS) return;
    int lo = 0, hi = N_NODES;
    while (lo < hi) { int m = (lo + hi) >> 1; if (batch[m] < g) lo = m + 1; else hi = m; }
    int lb = lo;
    lo = lb; hi = N_NODES;
    while (lo < hi) { int m = (lo + hi) >> 1; if (batch[m] < g + 1) lo = m + 1; else hi = m; }
    cnts[g] = (float)(lo - lb);
}

__global__ void zero2_kernel(float* __restrict__ p1, int n1, float* __restrict__ p2, int n2) {
    int i = blockIdx.x * blockDim.x + threadIdx.x;
    if (i < n1) p1[i] = 0.f;
    else if (i < n1 + n2) p2[i - n1] = 0.f;
}

__launch_bounds__(256)
__global__ void fc1_part(const float* __restrict__ sums, const float* __restrict__ cnts,
                         const float* __restrict__ fc1_w, float* __restrict__ F) {
    __shared__ float sv[64];
    int b = blockIdx.x;
    int g = b >> 3;
    int kc = b & 7;
    int t = threadIdx.x;
    if (t < 64) sv[t] = sums[(size_t)g * D_HID + kc * 64 + t] / fmaxf(cnts[g], 1.f);
    __syncthreads();
#pragma unroll
    for (int m = 0; m < D_FC / 256; ++m) {
        int j = t + m * 256;
        const float* wp = fc1_w + (size_t)(kc * 64) * D_FC + j;
        float acc = 0.f;
#pragma unroll
        for (int k = 0; k < 64; ++k) acc += sv[k] * wp[(size_t)k * D_FC];
        atomicAdd(&F[(size_t)g * D_FC + j], acc);
    }
}

__launch_bounds__(256)
__global__ void head_final(const float* __restrict__ F, const float* __restrict__ fc1_b,
                           const float* __restrict__ head_w, const float* __restrict__ head_b,
                           float* __restrict__ out) {
    __shared__ float hacc[N_CLS];
    int g = blockIdx.x;
    int t = threadIdx.x;
    if (t < N_CLS) hacc[t] = 0.f;
    __syncthreads();
    float p[N_CLS] = {};
    for (int j = t; j < D_FC; j += 256) {
        float f = fmaxf(F[(size_t)g * D_FC + j] + fc1_b[j], 0.f);
#pragma unroll
        for (int c = 0; c < N_CLS; ++c) p[c] += f * head_w[j * N_CLS + c];
    }
#pragma unroll
    for (int c = 0; c < N_CLS; ++c) {
        float v = p[c];
        for (int off = 32; off; off >>= 1) v += __shfl_down(v, off, 64);
        if ((t & 63) == 0) atomicAdd(&hacc[c], v);
    }
    __syncthreads();
    if (t < N_CLS) out[g * N_CLS + t] = hacc[t] + head_b[t];
}

extern "C" void kernel_launch(void* const* d_in, const int* in_sizes, int n_in,
                              void* d_out, int out_size, void* d_ws, size_t ws_size,
                              hipStream_t stream) {
    const float* x          = (const float*)d_in[0];
    const int*   edge_index = (const int*)d_in[1];
    const float* edge_attr  = (const float*)d_in[2];
    const int*   batch      = (const int*)d_in[3];
    const float* emb_w1 = (const float*)d_in[4];
    const float* emb_b1 = (const float*)d_in[5];
    const float* emb_w2 = (const float*)d_in[6];
    const float* emb_b2 = (const float*)d_in[7];
    const float* ep_w1  = (const float*)d_in[8];
    const float* ep_b1  = (const float*)d_in[9];
    const float* ep_w2  = (const float*)d_in[10];
    const float* ep_b2  = (const float*)d_in[11];
    const float* w_c[6] = { (const float*)d_in[12], (const float*)d_in[14], (const float*)d_in[16],
                            (const float*)d_in[18], (const float*)d_in[20], (const float*)d_in[22] };
    const float* b_c[6] = { (const float*)d_in[13], (const float*)d_in[15], (const float*)d_in[17],
                            (const float*)d_in[19], (const float*)d_in[21], (const float*)d_in[23] };
    const float* fc1_w  = (const float*)d_in[24];
    const float* fc1_b  = (const float*)d_in[25];
    const float* head_w = (const float*)d_in[26];
    const float* head_b = (const float*)d_in[27];
    float* out = (float*)d_out;

    const int* src = edge_index;
    const int* dst = edge_index + N_EDGES;

    char* p = (char*)d_ws;
    auto alloc = [&](size_t bytes) { char* r = p; p += (bytes + 255) & ~(size_t)255; return r; };
    float* ew    = (float*)alloc(N_EDGES * 4);
    float* deg   = (float*)alloc(N_NODES * 4);
    float* dinv  = (float*)alloc(N_NODES * 4);
    float* nloop = (float*)alloc(N_NODES * 4);
    int* cnt     = (int*)alloc(N_NODES * 4);
    int* cursor  = (int*)alloc(N_NODES * 4);
    int* rowptr  = (int*)alloc((N_NODES + 1) * 4);
    int2* cv     = (int2*)alloc((size_t)N_EDGES * 8);
    u16* xb = (u16*)alloc((size_t)MP * F_IN * 2);
    u16* H1 = (u16*)alloc((size_t)MP * D_EMB * 2);
    u16* H2 = (u16*)alloc((size_t)MP * D_EMB * 2);
    u16* G  = (u16*)alloc((size_t)MP * D_HID * 2);
    u16* S1 = (u16*)alloc((size_t)MP * D_HID * 2);
    u16* S2 = (u16*)alloc((size_t)MP * D_HID * 2);
    u16* Cb = (u16*)alloc((size_t)MP * D_HID * 2);
    u16* we1 = (u16*)alloc((size_t)F_IN * D_EMB * 2);
    u16* we2 = (u16*)alloc((size_t)D_EMB * D_EMB * 2);
    u16* wc[6];
    wc[0] = (u16*)alloc((size_t)D_EMB * D_HID * 2);
    for (int i = 1; i < 6; ++i) wc[i] = (u16*)alloc((size_t)D_HID * D_HID * 2);
    float* sums = (float*)alloc(N_GRAPHS * D_HID * 4);
    float* cnts = (float*)alloc(N_GRAPHS * 4);
    float* F    = (float*)alloc(N_GRAPHS * D_FC * 4);

    const int TB = 256;
    const int EB = (N_EDGES + TB - 1) / TB;
    const int NB = (N_NODES + TB - 1) / TB;

    init_kernel<<<NB, TB, 0, stream>>>(deg, cnt, cursor);
    edge_mlp_deg<<<EB, TB, 0, stream>>>(edge_attr, ep_w1, ep_b1, ep_w2, ep_b2, dst, ew, deg, cnt);
    dinv_kernel<<<NB, TB, 0, stream>>>(deg, dinv, nloop);
    scan_kernel<<<1, 1024, 0, stream>>>(cnt, rowptr);
    fill_csr_kernel<<<EB, TB, 0, stream>>>(src, dst, ew, dinv, rowptr, cursor, cv);

    xprep_kernel<<<(MP * F_IN + TB - 1) / TB, TB, 0, stream>>>(x, xb);
    gpad_zero<<<((MP - N_NODES) * D_HID + TB - 1) / TB, TB, 0, stream>>>(G);
    wprep_kernel<<<dim3(D_EMB / 32, F_IN / 32), dim3(32, 8), 0, stream>>>(emb_w1, we1, F_IN, D_EMB);
    wprep_kernel<<<dim3(D_EMB / 32, D_EMB / 32), dim3(32, 8), 0, stream>>>(emb_w2, we2, D_EMB, D_EMB);
    wprep_kernel<<<dim3(D_HID / 32, D_EMB / 32), dim3(32, 8), 0, stream>>>(w_c[0], wc[0], D_EMB, D_HID);
    for (int i = 1; i < 6; ++i)
        wprep_kernel<<<dim3(D_HID / 32, D_HID / 32), dim3(32, 8), 0, stream>>>(w_c[i], wc[i], D_HID, D_HID);

    const int SLOTS = ((NROWB + 7) / 8) * 8;        // 160
    const int GRID2 = SLOTS * (D_EMB / 128);        // 320
    const int GRID4 = SLOTS * (D_HID / 128);        // 640
    mfma_gemm<<<GRID2, 512, 0, stream>>>(xb, we1, emb_b1, nullptr, H1, F_IN, D_EMB);
    mfma_gemm<<<GRID2, 512, 0, stream>>>(H1, we2, emb_b2, nullptr, H2, D_EMB, D_EMB);

    const int GG = (N_NODES + 3) / 4;
    gather_f16<D_EMB><<<GG, 256, 0, stream>>>(H2, rowptr, cv, nloop, G);
    mfma_gemm<<<GRID4, 512, 0, stream>>>(G, wc[0], b_c[0], nullptr, S1, D_EMB, D_HID);
    gather_f16<D_HID><<<GG, 256, 0, stream>>>(S1, rowptr, cv, nloop, G);
    mfma_gemm<<<GRID4, 512, 0, stream>>>(G, wc[1], b_c[1], nullptr, Cb, D_HID, D_HID);
    gather_f16<D_HID><<<GG, 256, 0, stream>>>(Cb, rowptr, cv, nloop, G);
    mfma_gemm<<<GRID4, 512, 0, stream>>>(G, wc[2], b_c[2], S1, S2, D_HID, D_HID);
    gather_f16<D_HID><<<GG, 256, 0, stream>>>(S2, rowptr, cv, nloop, G);
    mfma_gemm<<<GRID4, 512, 0, stream>>>(G, wc[3], b_c[3], nullptr, Cb, D_HID, D_HID);
    gather_f16<D_HID><<<GG, 256, 0, stream>>>(Cb, rowptr, cv, nloop, G);
    mfma_gemm<<<GRID4, 512, 0, stream>>>(G, wc[4], b_c[4], nullptr, Cb, D_HID, D_HID);
    gather_f16<D_HID><<<GG, 256, 0, stream>>>(Cb, rowptr, cv, nloop, G);
    mfma_gemm<<<GRID4, 512, 0, stream>>>(G, wc[5], b_c[5], S2, Cb, D_HID, D_HID);

    zero2_kernel<<<(N_GRAPHS * (D_HID + D_FC) + TB - 1) / TB, TB, 0, stream>>>(
        sums, N_GRAPHS * D_HID, F, N_GRAPHS * D_FC);
    pool_sum_f16<<<((N_NODES / NP) * D_HID + TB - 1) / TB, TB, 0, stream>>>(Cb, batch, sums);
    graph_cnt_kernel<<<1, 64, 0, stream>>>(batch, cnts);
    fc1_part<<<N_GRAPHS * 8, 256, 0, stream>>>(sums, cnts, fc1_w, F);
    head_final<<<N_GRAPHS, 256, 0, stream>>>(F, fc1_b, head_w, head_b, out);
}